// Round 9
// baseline (1569.020 us; speedup 1.0000x reference)
//
#include <hip/hip_runtime.h>

typedef unsigned short u16;
typedef unsigned int u32;
typedef __attribute__((ext_vector_type(8))) short short8;
typedef __attribute__((ext_vector_type(8))) u16 ushort8;
typedef __attribute__((ext_vector_type(4))) float f32x4;

#define T_TOK 2048
#define H_DIM 2048
#define NEXP 64
#define I_DIM 1408
#define SI_DIM 2816
#define BM 128
#define BK 64
#define MAXT 256

__device__ __forceinline__ u16 f2bf(float f) {
    u32 u = __builtin_bit_cast(u32, f);
    u32 r = u + 0x7FFFu + ((u >> 16) & 1u);
    return (u16)(r >> 16);
}

__device__ __forceinline__ ushort8 cvt8(f32x4 a, f32x4 b) {
    ushort8 o;
    o[0] = f2bf(a[0]); o[1] = f2bf(a[1]); o[2] = f2bf(a[2]); o[3] = f2bf(a[3]);
    o[4] = f2bf(b[0]); o[5] = f2bf(b[1]); o[6] = f2bf(b[2]); o[7] = f2bf(b[3]);
    return o;
}

__device__ __forceinline__ f32x4 mfma16(short8 a, short8 b, f32x4 c) {
    return __builtin_amdgcn_mfma_f32_16x16x32_bf16(a, b, c, 0, 0, 0);
}

// ---------------- x -> bf16 ----------------
__global__ __launch_bounds__(256) void k_cvt(const float* __restrict__ x, u16* __restrict__ xb) {
    int i = (blockIdx.x * 256 + threadIdx.x) * 8;
    f32x4 v0 = *(const f32x4*)(x + i);
    f32x4 v1 = *(const f32x4*)(x + i + 4);
    *(ushort8*)(xb + i) = cvt8(v0, v1);
}

// ---------------- gating logits: f64 accumulation ----------------
__global__ __launch_bounds__(256) void k_gate_logits(const float* __restrict__ x,
        const float* __restrict__ gw, float* __restrict__ logits) {
    __shared__ float xs[8][65];
    __shared__ float wsh[64][65];
    int tid = threadIdx.x;
    int t0 = blockIdx.x * 8;
    double acc0 = 0.0, acc1 = 0.0;
    int e = tid & 63, tg = tid >> 6; // tg in [0,4)
    for (int k0 = 0; k0 < H_DIM; k0 += 64) {
        #pragma unroll
        for (int s = 0; s < 2; ++s) {
            int idx = s * 256 + tid;
            int r = idx >> 6, k = idx & 63;
            xs[r][k] = x[(size_t)(t0 + r) * H_DIM + k0 + k];
        }
        #pragma unroll
        for (int s = 0; s < 16; ++s) {
            int idx = s * 256 + tid;
            int r = idx >> 6, k = idx & 63;
            wsh[r][k] = gw[(size_t)r * H_DIM + k0 + k];
        }
        __syncthreads();
        #pragma unroll 8
        for (int k = 0; k < 64; ++k) {
            double wv = (double)wsh[e][k];
            acc0 += (double)xs[tg][k] * wv;
            acc1 += (double)xs[tg + 4][k] * wv;
        }
        __syncthreads();
    }
    logits[(size_t)(t0 + tg) * NEXP + e] = (float)acc0;
    logits[(size_t)(t0 + tg + 4) * NEXP + e] = (float)acc1;
}

// ---------------- per-token group-restricted top-k ----------------
__global__ __launch_bounds__(256) void k_topk(const float* __restrict__ logits,
        const float* __restrict__ ebias, int* __restrict__ topk_idx,
        float* __restrict__ topk_w, int* __restrict__ counts) {
    __shared__ float bsh[64];
    if (threadIdx.x < 64) bsh[threadIdx.x] = ebias[threadIdx.x];
    __syncthreads();
    int t = blockIdx.x * 256 + threadIdx.x;
    float sc[64];
    #pragma unroll
    for (int e2 = 0; e2 < 64; ++e2) {
        float lg = logits[(size_t)t * 64 + e2];
        sc[e2] = 1.0f / (1.0f + expf(-lg));
    }
    float gsc[8];
    #pragma unroll
    for (int g = 0; g < 8; ++g) {
        float m1 = -1e30f, m2 = -1e30f;
        #pragma unroll
        for (int j = 0; j < 8; ++j) {
            float v = sc[g * 8 + j] + bsh[g * 8 + j];
            if (v > m1) { m2 = m1; m1 = v; }
            else if (v > m2) { m2 = v; }
        }
        gsc[g] = m1 + m2;
    }
    u32 gmask = 0;
    #pragma unroll
    for (int it = 0; it < 4; ++it) {
        float best = -1e30f; int bi = 0;
        #pragma unroll
        for (int g = 0; g < 8; ++g) {
            bool ok = !((gmask >> g) & 1u);
            if (ok && gsc[g] > best) { best = gsc[g]; bi = g; }
        }
        gmask |= 1u << bi;
    }
    unsigned long long avail = 0ull;
    #pragma unroll
    for (int g = 0; g < 8; ++g)
        if ((gmask >> g) & 1u) avail |= (0xFFull << (g * 8));
    float wsum = 0.f;
    int idx[8]; float wv[8];
    #pragma unroll
    for (int it = 0; it < 8; ++it) {
        float best = -1e30f, bw = 0.f; int bi = 0;
        #pragma unroll
        for (int e2 = 0; e2 < 64; ++e2) {
            bool ok = (avail >> e2) & 1ull;
            float v = sc[e2] + bsh[e2];
            if (ok && v > best) { best = v; bi = e2; bw = sc[e2]; }
        }
        avail &= ~(1ull << bi);
        idx[it] = bi; wv[it] = bw; wsum += bw;
    }
    float scale = 2.5f / (wsum + 1e-20f);
    #pragma unroll
    for (int it = 0; it < 8; ++it) {
        topk_idx[t * 8 + it] = idx[it];
        topk_w[t * 8 + it] = wv[it] * scale;
        atomicAdd(&counts[idx[it]], 1);
    }
}

// ---------------- prefix sum + tile list (BM=128) ----------------
__global__ void k_prefix(const int* __restrict__ counts, int* __restrict__ offsets,
                         int* __restrict__ tiles, int* __restrict__ ntiles) {
    if (threadIdx.x == 0) {
        int run = 0, nt = 0;
        for (int e = 0; e < 64; ++e) {
            offsets[e] = run;
            int c = counts[e];
            for (int m0 = 0; m0 < c && nt < MAXT; m0 += BM) tiles[nt++] = (e << 16) | m0;
            run += c;
        }
        offsets[64] = run;
        *ntiles = nt;
    }
}

// ---------------- scatter (t,k) -> per-expert lists ----------------
__global__ __launch_bounds__(256) void k_scatter(const int* __restrict__ topk_idx,
        const float* __restrict__ topk_w, const int* __restrict__ offsets,
        int* __restrict__ fill, int* __restrict__ tok_list, float* __restrict__ w_list) {
    int gid = blockIdx.x * 256 + threadIdx.x;
    int t = gid >> 3;
    int e = topk_idx[gid];
    int pos = offsets[e] + atomicAdd(&fill[e], 1);
    tok_list[pos] = t;
    w_list[pos] = topk_w[gid];
}

// ---------------- fused gate+up+silu*mul grouped GEMM ----------------
// 128m x 64n(gate+up), BK=64, 4 waves (each 32m x 64n x {g,u}).
// A: global->register direct, double-buffered (no LDS; no inter-wave A reuse).
// B: f32->bf16 reg-staged into double-buffered swizzled LDS; one barrier/K-step.
__global__ __launch_bounds__(256, 3) void k_gateup(
        const u16* __restrict__ xb,
        const float* __restrict__ gate_base, const float* __restrict__ up_base,
        const int* __restrict__ offsets, const int* __restrict__ tok_list,
        const int* __restrict__ tiles, const int* __restrict__ ntiles,
        u16* __restrict__ inter, int Irows) {
    int e, m0, seg, n;
    if (tiles) {
        if ((int)blockIdx.x >= *ntiles) return;
        int tt = tiles[blockIdx.x];
        e = tt >> 16; m0 = tt & 0xFFFF;
        seg = offsets[e]; n = offsets[e + 1] - seg;
    } else {
        e = 0; m0 = blockIdx.x * BM; seg = 0; n = T_TOK;
    }
    if (n <= 0 || m0 >= n) return;
    int i0 = blockIdx.y * 64;

    const float* Bg = gate_base + (size_t)e * Irows * H_DIM;
    const float* Bu = up_base + (size_t)e * Irows * H_DIM;
    const char* xbc = (const char*)xb;

    __shared__ u16 Bsg[2][64 * BK];   // 2 x 8KB
    __shared__ u16 Bsu[2][64 * BK];   // 2 x 8KB

    int tid = threadIdx.x;
    int w = tid >> 6, lane = tid & 63;

    // A fragment offsets (bytes from xb): [fm][ks], advance 128B per K-step
    u32 aoff[2][2];
    {
        int rbase = w * 32 + (lane & 15);
        #pragma unroll
        for (int fm = 0; fm < 2; ++fm) {
            int p = m0 + rbase + fm * 16; if (p >= n) p = n - 1;
            int tok = tok_list ? tok_list[seg + p] : p;
            u32 base = (u32)tok * (H_DIM * 2) + ((lane >> 4) * 16);
            aoff[fm][0] = base;
            aoff[fm][1] = base + 64;
        }
    }
    // B staging: 2 slots/thread/matrix (r 0..63, cb 0..7)
    const float* bgsrc[2]; const float* busrc[2]; int bdst[2];
    #pragma unroll
    for (int s = 0; s < 2; ++s) {
        int slot = s * 256 + tid;
        int r = slot >> 3, cb = slot & 7;
        bgsrc[s] = Bg + (size_t)(i0 + r) * H_DIM + cb * 8;
        busrc[s] = Bu + (size_t)(i0 + r) * H_DIM + cb * 8;
        bdst[s] = r * BK + ((cb ^ (r & 7)) * 8);
    }

    f32x4 zero; zero[0] = 0.f; zero[1] = 0.f; zero[2] = 0.f; zero[3] = 0.f;
    f32x4 accg[2][4], accu[2][4];
    #pragma unroll
    for (int a = 0; a < 2; ++a)
        #pragma unroll
        for (int b = 0; b < 4; ++b) { accg[a][b] = zero; accu[a][b] = zero; }

    short8 aX[2][2], aY[2][2];
    f32x4 stG[2][2], stU[2][2];

    auto ldA = [&](int t, short8 (&A)[2][2]) {
        u32 kb = (u32)t * (BK * 2);
        #pragma unroll
        for (int fm = 0; fm < 2; ++fm)
            #pragma unroll
            for (int ks = 0; ks < 2; ++ks)
                A[fm][ks] = *(const short8*)(xbc + (size_t)(aoff[fm][ks] + kb));
    };
    auto ldB = [&](int t) {
        int k0 = t * BK;
        #pragma unroll
        for (int s = 0; s < 2; ++s) {
            stG[s][0] = *(const f32x4*)(bgsrc[s] + k0);
            stG[s][1] = *(const f32x4*)(bgsrc[s] + k0 + 4);
            stU[s][0] = *(const f32x4*)(busrc[s] + k0);
            stU[s][1] = *(const f32x4*)(busrc[s] + k0 + 4);
        }
    };
    auto dswrite = [&](int buf) {
        #pragma unroll
        for (int s = 0; s < 2; ++s) {
            *(ushort8*)(&Bsg[buf][bdst[s]]) = cvt8(stG[s][0], stG[s][1]);
            *(ushort8*)(&Bsu[buf][bdst[s]]) = cvt8(stU[s][0], stU[s][1]);
        }
    };
    auto mmaStep = [&](short8 (&A)[2][2], int buf) {
        #pragma unroll
        for (int ks = 0; ks < 2; ++ks) {
            #pragma unroll
            for (int fn = 0; fn < 4; ++fn) {
                int brow = fn * 16 + (lane & 15);
                int cb = ks * 4 + (lane >> 4);
                int boff = brow * BK + ((cb ^ (brow & 7)) * 8);
                short8 bg = *(const short8*)(&Bsg[buf][boff]);
                short8 bu = *(const short8*)(&Bsu[buf][boff]);
                accg[0][fn] = mfma16(A[0][ks], bg, accg[0][fn]);
                accg[1][fn] = mfma16(A[1][ks], bg, accg[1][fn]);
                accu[0][fn] = mfma16(A[0][ks], bu, accu[0][fn]);
                accu[1][fn] = mfma16(A[1][ks], bu, accu[1][fn]);
            }
        }
    };

    const int NK = H_DIM / BK; // 32, even
    ldA(0, aX);
    ldB(0);
    dswrite(0);
    __syncthreads();
    for (int t = 0; t < NK; t += 2) {
        // even: aX, buf0
        if (t + 1 < NK) { ldB(t + 1); ldA(t + 1, aY); }
        mmaStep(aX, 0);
        if (t + 1 < NK) dswrite(1);
        __syncthreads();
        if (t + 1 < NK) {
            // odd: aY, buf1
            if (t + 2 < NK) { ldB(t + 2); ldA(t + 2, aX); }
            mmaStep(aY, 1);
            if (t + 2 < NK) dswrite(0);
            __syncthreads();
        }
    }

    int r0 = (lane >> 4) * 4, cc = lane & 15;
    #pragma unroll
    for (int fm = 0; fm < 2; ++fm) {
        #pragma unroll
        for (int r = 0; r < 4; ++r) {
            int p = m0 + w * 32 + fm * 16 + r0 + r;
            if (p < n) {
                size_t rowb = (size_t)(seg + p) * Irows + i0;
                #pragma unroll
                for (int fn = 0; fn < 4; ++fn) {
                    float g = accg[fm][fn][r], u = accu[fm][fn][r];
                    float val = g / (1.0f + expf(-g)) * u;
                    inter[rowb + fn * 16 + cc] = f2bf(val);
                }
            }
        }
    }
}

// ---------------- down-proj grouped GEMM ----------------
// 128m x 128n, BK=64, 4 waves (each 32m x 128n). A direct-to-reg dbuf; B LDS dbuf.
// w_list==nullptr => plain store (shared experts, run FIRST); else atomicAdd*wt.
__global__ __launch_bounds__(256, 3) void k_down(
        const u16* __restrict__ inter, int Kdim,
        const float* __restrict__ down_base,
        const int* __restrict__ offsets, const int* __restrict__ tok_list,
        const int* __restrict__ tiles, const int* __restrict__ ntiles,
        const float* __restrict__ w_list,
        float* __restrict__ out) {
    int e, m0, seg, n;
    if (tiles) {
        if ((int)blockIdx.x >= *ntiles) return;
        int tt = tiles[blockIdx.x];
        e = tt >> 16; m0 = tt & 0xFFFF;
        seg = offsets[e]; n = offsets[e + 1] - seg;
    } else {
        e = 0; m0 = blockIdx.x * BM; seg = 0; n = T_TOK;
    }
    if (n <= 0 || m0 >= n) return;
    int h0 = blockIdx.y * 128;

    const float* Bd = down_base + (size_t)e * H_DIM * Kdim;
    const char* aic = (const char*)inter;

    __shared__ u16 Bs[2][128 * BK];   // 2 x 16KB

    int tid = threadIdx.x;
    int w = tid >> 6, lane = tid & 63;

    u32 aoff[2][2];
    {
        int rbase = w * 32 + (lane & 15);
        #pragma unroll
        for (int fm = 0; fm < 2; ++fm) {
            int p = m0 + rbase + fm * 16; if (p >= n) p = n - 1;
            u32 base = (u32)(seg + p) * (Kdim * 2) + ((lane >> 4) * 16);
            aoff[fm][0] = base;
            aoff[fm][1] = base + 64;
        }
    }
    const float* bsrc[4]; int bdst[4];
    #pragma unroll
    for (int s = 0; s < 4; ++s) {
        int slot = s * 256 + tid;
        int r = slot >> 3, cb = slot & 7;
        bsrc[s] = Bd + (size_t)(h0 + r) * Kdim + cb * 8;
        bdst[s] = r * BK + ((cb ^ (r & 7)) * 8);
    }

    f32x4 zero; zero[0] = 0.f; zero[1] = 0.f; zero[2] = 0.f; zero[3] = 0.f;
    f32x4 acc[2][8];
    #pragma unroll
    for (int a = 0; a < 2; ++a)
        #pragma unroll
        for (int b = 0; b < 8; ++b) acc[a][b] = zero;

    short8 aX[2][2], aY[2][2];
    f32x4 stB[4][2];

    auto ldA = [&](int t, short8 (&A)[2][2]) {
        u32 kb = (u32)t * (BK * 2);
        #pragma unroll
        for (int fm = 0; fm < 2; ++fm)
            #pragma unroll
            for (int ks = 0; ks < 2; ++ks)
                A[fm][ks] = *(const short8*)(aic + (size_t)(aoff[fm][ks] + kb));
    };
    auto ldB = [&](int t) {
        int k0 = t * BK;
        #pragma unroll
        for (int s = 0; s < 4; ++s) {
            stB[s][0] = *(const f32x4*)(bsrc[s] + k0);
            stB[s][1] = *(const f32x4*)(bsrc[s] + k0 + 4);
        }
    };
    auto dswrite = [&](int buf) {
        #pragma unroll
        for (int s = 0; s < 4; ++s)
            *(ushort8*)(&Bs[buf][bdst[s]]) = cvt8(stB[s][0], stB[s][1]);
    };
    auto mmaStep = [&](short8 (&A)[2][2], int buf) {
        #pragma unroll
        for (int ks = 0; ks < 2; ++ks) {
            #pragma unroll
            for (int fn = 0; fn < 8; ++fn) {
                int brow = fn * 16 + (lane & 15);
                int cb = ks * 4 + (lane >> 4);
                short8 b = *(const short8*)(&Bs[buf][brow * BK + ((cb ^ (brow & 7)) * 8)]);
                acc[0][fn] = mfma16(A[0][ks], b, acc[0][fn]);
                acc[1][fn] = mfma16(A[1][ks], b, acc[1][fn]);
            }
        }
    };

    const int NK = Kdim / BK; // 22 or 44, even
    ldA(0, aX);
    ldB(0);
    dswrite(0);
    __syncthreads();
    for (int t = 0; t < NK; t += 2) {
        if (t + 1 < NK) { ldB(t + 1); ldA(t + 1, aY); }
        mmaStep(aX, 0);
        if (t + 1 < NK) dswrite(1);
        __syncthreads();
        if (t + 1 < NK) {
            if (t + 2 < NK) { ldB(t + 2); ldA(t + 2, aX); }
            mmaStep(aY, 1);
            if (t + 2 < NK) dswrite(0);
            __syncthreads();
        }
    }

    int r0 = (lane >> 4) * 4, cc = lane & 15;
    #pragma unroll
    for (int fm = 0; fm < 2; ++fm) {
        #pragma unroll
        for (int r = 0; r < 4; ++r) {
            int p = m0 + w * 32 + fm * 16 + r0 + r;
            if (p < n) {
                int tok = tok_list ? tok_list[seg + p] : p;
                size_t ob = (size_t)tok * H_DIM + h0 + cc;
                if (w_list) {
                    float wt = w_list[seg + p];
                    #pragma unroll
                    for (int fn = 0; fn < 8; ++fn)
                        atomicAdd(&out[ob + fn * 16], acc[fm][fn][r] * wt);
                } else {
                    #pragma unroll
                    for (int fn = 0; fn < 8; ++fn)
                        out[ob + fn * 16] = acc[fm][fn][r];
                }
            }
        }
    }
}

extern "C" void kernel_launch(void* const* d_in, const int* in_sizes, int n_in,
                              void* d_out, int out_size, void* d_ws, size_t ws_size,
                              hipStream_t stream) {
    const float* x         = (const float*)d_in[0];
    const float* gate_w    = (const float*)d_in[1];
    const float* e_bias    = (const float*)d_in[2];
    const float* gate_proj = (const float*)d_in[3];
    const float* up_proj   = (const float*)d_in[4];
    const float* down_proj = (const float*)d_in[5];
    const float* sgw       = (const float*)d_in[6];
    const float* suw       = (const float*)d_in[7];
    const float* sdw       = (const float*)d_in[8];
    float* out = (float*)d_out;

    char* ws = (char*)d_ws;
    size_t off = 0;
    auto alloc = [&](size_t bytes) -> char* {
        char* p = ws + off;
        off += (bytes + 255) & ~(size_t)255;
        return p;
    };
    float* logits   = (float*)alloc((size_t)T_TOK * 64 * 4);
    int*   topk_idx = (int*)  alloc((size_t)T_TOK * 8 * 4);
    float* topk_w   = (float*)alloc((size_t)T_TOK * 8 * 4);
    int*   counts   = (int*)  alloc(256);   // [64]
    int*   offsets  = (int*)  alloc(512);   // [65]
    int*   fill     = (int*)  alloc(256);   // [64]
    int*   tiles    = (int*)  alloc(MAXT * 4);
    int*   ntiles   = (int*)  alloc(256);
    int*   tok_list = (int*)  alloc((size_t)T_TOK * 8 * 4);
    float* w_list   = (float*)alloc((size_t)T_TOK * 8 * 4);
    u16*   xb       = (u16*)  alloc((size_t)T_TOK * H_DIM * 2);
    u16*   inter    = (u16*)  alloc((size_t)T_TOK * 8 * I_DIM * 2); // reused for shared

    hipMemsetAsync(counts, 0, 1024, stream); // counts + offsets + fill

    k_cvt<<<(T_TOK * H_DIM) / 2048, 256, 0, stream>>>(x, xb);
    k_gate_logits<<<T_TOK / 8, 256, 0, stream>>>(x, gate_w, logits);
    k_topk<<<T_TOK / 256, 256, 0, stream>>>(logits, e_bias, topk_idx, topk_w, counts);
    k_prefix<<<1, 64, 0, stream>>>(counts, offsets, tiles, ntiles);
    k_scatter<<<(T_TOK * 8) / 256, 256, 0, stream>>>(topk_idx, topk_w, offsets, fill, tok_list, w_list);

    // shared experts FIRST: shared k_down does plain stores covering all of out
    k_gateup<<<dim3(T_TOK / BM, SI_DIM / 64), 256, 0, stream>>>(
        xb, sgw, suw, nullptr, nullptr, nullptr, nullptr, inter, SI_DIM);
    k_down<<<dim3(T_TOK / BM, H_DIM / 128), 256, 0, stream>>>(
        inter, SI_DIM, sdw, nullptr, nullptr, nullptr, nullptr, nullptr, out);

    // routed experts accumulate on top via atomics
    k_gateup<<<dim3(MAXT, I_DIM / 64), 256, 0, stream>>>(
        xb, gate_proj, up_proj, offsets, tok_list, tiles, ntiles, inter, I_DIM);
    k_down<<<dim3(MAXT, H_DIM / 128), 256, 0, stream>>>(
        inter, I_DIM, down_proj, offsets, tok_list, tiles, ntiles, w_list, out);
}

// Round 10
// 1310.982 us; speedup vs baseline: 1.1968x; 1.1968x over previous
//
#include <hip/hip_runtime.h>

typedef unsigned short u16;
typedef unsigned int u32;
typedef __attribute__((ext_vector_type(8))) short short8;
typedef __attribute__((ext_vector_type(8))) u16 ushort8;
typedef __attribute__((ext_vector_type(4))) float f32x4;

#define T_TOK 2048
#define H_DIM 2048
#define NEXP 64
#define I_DIM 1408
#define SI_DIM 2816
#define BM 128
#define BK 64
#define MAXT 256

__device__ __forceinline__ u16 f2bf(float f) {
    u32 u = __builtin_bit_cast(u32, f);
    u32 r = u + 0x7FFFu + ((u >> 16) & 1u);
    return (u16)(r >> 16);
}

__device__ __forceinline__ ushort8 cvt8(f32x4 a, f32x4 b) {
    ushort8 o;
    o[0] = f2bf(a[0]); o[1] = f2bf(a[1]); o[2] = f2bf(a[2]); o[3] = f2bf(a[3]);
    o[4] = f2bf(b[0]); o[5] = f2bf(b[1]); o[6] = f2bf(b[2]); o[7] = f2bf(b[3]);
    return o;
}

__device__ __forceinline__ f32x4 mfma16(short8 a, short8 b, f32x4 c) {
    return __builtin_amdgcn_mfma_f32_16x16x32_bf16(a, b, c, 0, 0, 0);
}

// ---------------- x -> bf16 ----------------
__global__ __launch_bounds__(256) void k_cvt(const float* __restrict__ x, u16* __restrict__ xb) {
    int i = (blockIdx.x * 256 + threadIdx.x) * 8;
    f32x4 v0 = *(const f32x4*)(x + i);
    f32x4 v1 = *(const f32x4*)(x + i + 4);
    *(ushort8*)(xb + i) = cvt8(v0, v1);
}

// ---------------- gating logits: f64 accumulation ----------------
__global__ __launch_bounds__(256) void k_gate_logits(const float* __restrict__ x,
        const float* __restrict__ gw, float* __restrict__ logits) {
    __shared__ float xs[8][65];
    __shared__ float wsh[64][65];
    int tid = threadIdx.x;
    int t0 = blockIdx.x * 8;
    double acc0 = 0.0, acc1 = 0.0;
    int e = tid & 63, tg = tid >> 6; // tg in [0,4)
    for (int k0 = 0; k0 < H_DIM; k0 += 64) {
        #pragma unroll
        for (int s = 0; s < 2; ++s) {
            int idx = s * 256 + tid;
            int r = idx >> 6, k = idx & 63;
            xs[r][k] = x[(size_t)(t0 + r) * H_DIM + k0 + k];
        }
        #pragma unroll
        for (int s = 0; s < 16; ++s) {
            int idx = s * 256 + tid;
            int r = idx >> 6, k = idx & 63;
            wsh[r][k] = gw[(size_t)r * H_DIM + k0 + k];
        }
        __syncthreads();
        #pragma unroll 8
        for (int k = 0; k < 64; ++k) {
            double wv = (double)wsh[e][k];
            acc0 += (double)xs[tg][k] * wv;
            acc1 += (double)xs[tg + 4][k] * wv;
        }
        __syncthreads();
    }
    logits[(size_t)(t0 + tg) * NEXP + e] = (float)acc0;
    logits[(size_t)(t0 + tg + 4) * NEXP + e] = (float)acc1;
}

// ---------------- per-token group-restricted top-k ----------------
__global__ __launch_bounds__(256) void k_topk(const float* __restrict__ logits,
        const float* __restrict__ ebias, int* __restrict__ topk_idx,
        float* __restrict__ topk_w, int* __restrict__ counts) {
    __shared__ float bsh[64];
    if (threadIdx.x < 64) bsh[threadIdx.x] = ebias[threadIdx.x];
    __syncthreads();
    int t = blockIdx.x * 256 + threadIdx.x;
    float sc[64];
    #pragma unroll
    for (int e2 = 0; e2 < 64; ++e2) {
        float lg = logits[(size_t)t * 64 + e2];
        sc[e2] = 1.0f / (1.0f + expf(-lg));
    }
    float gsc[8];
    #pragma unroll
    for (int g = 0; g < 8; ++g) {
        float m1 = -1e30f, m2 = -1e30f;
        #pragma unroll
        for (int j = 0; j < 8; ++j) {
            float v = sc[g * 8 + j] + bsh[g * 8 + j];
            if (v > m1) { m2 = m1; m1 = v; }
            else if (v > m2) { m2 = v; }
        }
        gsc[g] = m1 + m2;
    }
    u32 gmask = 0;
    #pragma unroll
    for (int it = 0; it < 4; ++it) {
        float best = -1e30f; int bi = 0;
        #pragma unroll
        for (int g = 0; g < 8; ++g) {
            bool ok = !((gmask >> g) & 1u);
            if (ok && gsc[g] > best) { best = gsc[g]; bi = g; }
        }
        gmask |= 1u << bi;
    }
    unsigned long long avail = 0ull;
    #pragma unroll
    for (int g = 0; g < 8; ++g)
        if ((gmask >> g) & 1u) avail |= (0xFFull << (g * 8));
    float wsum = 0.f;
    int idx[8]; float wv[8];
    #pragma unroll
    for (int it = 0; it < 8; ++it) {
        float best = -1e30f, bw = 0.f; int bi = 0;
        #pragma unroll
        for (int e2 = 0; e2 < 64; ++e2) {
            bool ok = (avail >> e2) & 1ull;
            float v = sc[e2] + bsh[e2];
            if (ok && v > best) { best = v; bi = e2; bw = sc[e2]; }
        }
        avail &= ~(1ull << bi);
        idx[it] = bi; wv[it] = bw; wsum += bw;
    }
    float scale = 2.5f / (wsum + 1e-20f);
    #pragma unroll
    for (int it = 0; it < 8; ++it) {
        topk_idx[t * 8 + it] = idx[it];
        topk_w[t * 8 + it] = wv[it] * scale;
        atomicAdd(&counts[idx[it]], 1);
    }
}

// ---------------- prefix sum + XCD-grouped tile list (BM=128) ----------------
// Expert e's tiles all placed at positions == (e%8) mod 8 so every block of an
// expert lands on one XCD (gridX=MAXT is a multiple of 8) -> B/A panels are
// fetched into that XCD's L2 once instead of per-tile.
__global__ void k_prefix(const int* __restrict__ counts, int* __restrict__ offsets,
                         int* __restrict__ tiles, int* __restrict__ ntiles) {
    if (threadIdx.x == 0) {
        int run = 0;
        for (int e = 0; e < 64; ++e) { offsets[e] = run; run += counts[e]; }
        offsets[64] = run;
        for (int i = 0; i < MAXT; ++i) tiles[i] = -1;
        int slot[8] = {0, 0, 0, 0, 0, 0, 0, 0};
        int nt = 0;
        for (int e = 0; e < 64; ++e) {
            int xcd = e & 7;
            int c = counts[e];
            for (int m0 = 0; m0 < c; m0 += BM) {
                int pos = xcd + 8 * slot[xcd];
                if (pos < MAXT) { tiles[pos] = (e << 16) | m0; slot[xcd]++; nt++; }
            }
        }
        *ntiles = nt;
    }
}

// ---------------- scatter (t,k) -> per-expert lists ----------------
__global__ __launch_bounds__(256) void k_scatter(const int* __restrict__ topk_idx,
        const float* __restrict__ topk_w, const int* __restrict__ offsets,
        int* __restrict__ fill, int* __restrict__ tok_list, float* __restrict__ w_list) {
    int gid = blockIdx.x * 256 + threadIdx.x;
    int t = gid >> 3;
    int e = topk_idx[gid];
    int pos = offsets[e] + atomicAdd(&fill[e], 1);
    tok_list[pos] = t;
    w_list[pos] = topk_w[gid];
}

// ---------------- fused gate+up+silu*mul grouped GEMM ----------------
// 128m x 64n(gate+up), BK=64, 4 waves (each 32m x 64n x {g,u}).
// Double-buffered LDS, ONE barrier per K-step, compiler-scheduled prefetch.
// Routed: x = XCD-grouped tile (sentinel -1), y = i0 panel.
// Shared: x = i0 panel (padded grid, xcd = i0%8), y = m-tile -> all m-tiles of a
// panel share one XCD's L2 copy of B.
__global__ __launch_bounds__(256, 2) void k_gateup(
        const u16* __restrict__ xb,
        const float* __restrict__ gate_base, const float* __restrict__ up_base,
        const int* __restrict__ offsets, const int* __restrict__ tok_list,
        const int* __restrict__ tiles, const int* __restrict__ ntiles,
        u16* __restrict__ inter, int Irows) {
    int e, m0, seg, n, i0;
    if (tiles) {
        int tt = tiles[blockIdx.x];
        if (tt < 0) return;
        e = tt >> 16; m0 = tt & 0xFFFF;
        seg = offsets[e]; n = offsets[e + 1] - seg;
        i0 = blockIdx.y * 64;
    } else {
        e = 0; seg = 0; n = T_TOK;
        i0 = blockIdx.x * 64;
        if (i0 >= Irows) return;
        m0 = blockIdx.y * BM;
    }
    if (n <= 0 || m0 >= n) return;

    const float* Bg = gate_base + (size_t)e * Irows * H_DIM;
    const float* Bu = up_base + (size_t)e * Irows * H_DIM;

    __shared__ u16 As[2][BM * BK];    // 2 x 16KB
    __shared__ u16 Bsg[2][64 * BK];   // 2 x 8KB
    __shared__ u16 Bsu[2][64 * BK];   // 2 x 8KB

    int tid = threadIdx.x;
    int w = tid >> 6, lane = tid & 63;

    // A: 1024 slots (r 0..127, cb 0..7), 4 slots/thread
    const u16* asrc[4]; int adst[4];
    #pragma unroll
    for (int s = 0; s < 4; ++s) {
        int slot = s * 256 + tid;
        int r = slot >> 3, cb = slot & 7;
        int p = m0 + r; if (p >= n) p = n - 1;
        int tok = tok_list ? tok_list[seg + p] : p;
        asrc[s] = xb + (size_t)tok * H_DIM + cb * 8;
        adst[s] = r * BK + ((cb ^ (r & 7)) * 8);
    }
    // B: 512 slots per matrix (r 0..63, cb 0..7), 2 slots/thread/matrix
    const float* bgsrc[2]; const float* busrc[2]; int bdst[2];
    #pragma unroll
    for (int s = 0; s < 2; ++s) {
        int slot = s * 256 + tid;
        int r = slot >> 3, cb = slot & 7;
        bgsrc[s] = Bg + (size_t)(i0 + r) * H_DIM + cb * 8;
        busrc[s] = Bu + (size_t)(i0 + r) * H_DIM + cb * 8;
        bdst[s] = r * BK + ((cb ^ (r & 7)) * 8);
    }

    f32x4 zero; zero[0] = 0.f; zero[1] = 0.f; zero[2] = 0.f; zero[3] = 0.f;
    f32x4 accg[2][4], accu[2][4];
    #pragma unroll
    for (int a = 0; a < 2; ++a)
        #pragma unroll
        for (int b = 0; b < 4; ++b) { accg[a][b] = zero; accu[a][b] = zero; }

    // staged regs (statically indexed)
    short8 stA[4];
    f32x4 stG[2][2], stU[2][2];

    auto ldregs = [&](int k0) {
        #pragma unroll
        for (int s = 0; s < 4; ++s) stA[s] = *(const short8*)(asrc[s] + k0);
        #pragma unroll
        for (int s = 0; s < 2; ++s) {
            stG[s][0] = *(const f32x4*)(bgsrc[s] + k0);
            stG[s][1] = *(const f32x4*)(bgsrc[s] + k0 + 4);
            stU[s][0] = *(const f32x4*)(busrc[s] + k0);
            stU[s][1] = *(const f32x4*)(busrc[s] + k0 + 4);
        }
    };
    auto dswrite = [&](int buf) {
        #pragma unroll
        for (int s = 0; s < 4; ++s) *(ushort8*)(&As[buf][adst[s]]) = *(const ushort8*)&stA[s];
        #pragma unroll
        for (int s = 0; s < 2; ++s) {
            *(ushort8*)(&Bsg[buf][bdst[s]]) = cvt8(stG[s][0], stG[s][1]);
            *(ushort8*)(&Bsu[buf][bdst[s]]) = cvt8(stU[s][0], stU[s][1]);
        }
    };
    auto mmaStep = [&](int buf) {
        #pragma unroll
        for (int ks = 0; ks < 2; ++ks) {
            short8 a[2];
            #pragma unroll
            for (int fm = 0; fm < 2; ++fm) {
                int row = w * 32 + fm * 16 + (lane & 15);
                int cb = ks * 4 + (lane >> 4);
                a[fm] = *(const short8*)(&As[buf][row * BK + ((cb ^ (row & 7)) * 8)]);
            }
            #pragma unroll
            for (int fn = 0; fn < 4; ++fn) {
                int brow = fn * 16 + (lane & 15);
                int cb = ks * 4 + (lane >> 4);
                int boff = brow * BK + ((cb ^ (brow & 7)) * 8);
                short8 bg = *(const short8*)(&Bsg[buf][boff]);
                short8 bu = *(const short8*)(&Bsu[buf][boff]);
                accg[0][fn] = mfma16(a[0], bg, accg[0][fn]);
                accg[1][fn] = mfma16(a[1], bg, accg[1][fn]);
                accu[0][fn] = mfma16(a[0], bu, accu[0][fn]);
                accu[1][fn] = mfma16(a[1], bu, accu[1][fn]);
            }
        }
    };

    const int NK = H_DIM / BK; // 32
    ldregs(0);
    dswrite(0);
    __syncthreads();
    for (int t = 0; t < NK; ++t) {
        if (t + 1 < NK) ldregs((t + 1) * BK);
        mmaStep(t & 1);
        if (t + 1 < NK) dswrite((t + 1) & 1);
        __syncthreads();
    }

    int r0 = (lane >> 4) * 4, cc = lane & 15;
    #pragma unroll
    for (int fm = 0; fm < 2; ++fm) {
        #pragma unroll
        for (int r = 0; r < 4; ++r) {
            int p = m0 + w * 32 + fm * 16 + r0 + r;
            if (p < n) {
                size_t rowb = (size_t)(seg + p) * Irows + i0;
                #pragma unroll
                for (int fn = 0; fn < 4; ++fn) {
                    float g = accg[fm][fn][r], u = accu[fm][fn][r];
                    float val = g / (1.0f + expf(-g)) * u;
                    inter[rowb + fn * 16 + cc] = f2bf(val);
                }
            }
        }
    }
}

// ---------------- down-proj grouped GEMM ----------------
// 128m x 128n, BK=64, 4 waves (each 32m x 128n). Same dbuf single-barrier scheme.
// Routed: x = XCD-grouped tile, y = h0. Shared: x = h0 (16, mult of 8), y = m-tile.
// w_list==nullptr => plain store (shared experts, run FIRST); else atomicAdd*wt.
__global__ __launch_bounds__(256, 2) void k_down(
        const u16* __restrict__ inter, int Kdim,
        const float* __restrict__ down_base,
        const int* __restrict__ offsets, const int* __restrict__ tok_list,
        const int* __restrict__ tiles, const int* __restrict__ ntiles,
        const float* __restrict__ w_list,
        float* __restrict__ out) {
    int e, m0, seg, n, h0;
    if (tiles) {
        int tt = tiles[blockIdx.x];
        if (tt < 0) return;
        e = tt >> 16; m0 = tt & 0xFFFF;
        seg = offsets[e]; n = offsets[e + 1] - seg;
        h0 = blockIdx.y * 128;
    } else {
        e = 0; seg = 0; n = T_TOK;
        h0 = blockIdx.x * 128;
        m0 = blockIdx.y * BM;
    }
    if (n <= 0 || m0 >= n) return;

    const float* Bd = down_base + (size_t)e * H_DIM * Kdim;

    __shared__ u16 As[2][BM * BK];    // 2 x 16KB
    __shared__ u16 Bs[2][128 * BK];   // 2 x 16KB

    int tid = threadIdx.x;
    int w = tid >> 6, lane = tid & 63;

    const u16* asrc[4]; int adst[4];
    #pragma unroll
    for (int s = 0; s < 4; ++s) {
        int slot = s * 256 + tid;
        int r = slot >> 3, cb = slot & 7;
        int p = m0 + r; if (p >= n) p = n - 1;
        asrc[s] = inter + (size_t)(seg + p) * Kdim + cb * 8;
        adst[s] = r * BK + ((cb ^ (r & 7)) * 8);
    }
    const float* bsrc[4]; int bdst[4];
    #pragma unroll
    for (int s = 0; s < 4; ++s) {
        int slot = s * 256 + tid;
        int r = slot >> 3, cb = slot & 7;
        bsrc[s] = Bd + (size_t)(h0 + r) * Kdim + cb * 8;
        bdst[s] = r * BK + ((cb ^ (r & 7)) * 8);
    }

    f32x4 zero; zero[0] = 0.f; zero[1] = 0.f; zero[2] = 0.f; zero[3] = 0.f;
    f32x4 acc[2][8];
    #pragma unroll
    for (int a = 0; a < 2; ++a)
        #pragma unroll
        for (int b = 0; b < 8; ++b) acc[a][b] = zero;

    short8 stA[4];
    f32x4 stB[4][2];

    auto ldregs = [&](int k0) {
        #pragma unroll
        for (int s = 0; s < 4; ++s) stA[s] = *(const short8*)(asrc[s] + k0);
        #pragma unroll
        for (int s = 0; s < 4; ++s) {
            stB[s][0] = *(const f32x4*)(bsrc[s] + k0);
            stB[s][1] = *(const f32x4*)(bsrc[s] + k0 + 4);
        }
    };
    auto dswrite = [&](int buf) {
        #pragma unroll
        for (int s = 0; s < 4; ++s) *(ushort8*)(&As[buf][adst[s]]) = *(const ushort8*)&stA[s];
        #pragma unroll
        for (int s = 0; s < 4; ++s)
            *(ushort8*)(&Bs[buf][bdst[s]]) = cvt8(stB[s][0], stB[s][1]);
    };
    auto mmaStep = [&](int buf) {
        #pragma unroll
        for (int ks = 0; ks < 2; ++ks) {
            short8 a[2];
            #pragma unroll
            for (int fm = 0; fm < 2; ++fm) {
                int row = w * 32 + fm * 16 + (lane & 15);
                int cb = ks * 4 + (lane >> 4);
                a[fm] = *(const short8*)(&As[buf][row * BK + ((cb ^ (row & 7)) * 8)]);
            }
            #pragma unroll
            for (int fn = 0; fn < 8; ++fn) {
                int brow = fn * 16 + (lane & 15);
                int cb = ks * 4 + (lane >> 4);
                short8 b = *(const short8*)(&Bs[buf][brow * BK + ((cb ^ (brow & 7)) * 8)]);
                acc[0][fn] = mfma16(a[0], b, acc[0][fn]);
                acc[1][fn] = mfma16(a[1], b, acc[1][fn]);
            }
        }
    };

    const int NK = Kdim / BK; // 22 or 44
    ldregs(0);
    dswrite(0);
    __syncthreads();
    for (int t = 0; t < NK; ++t) {
        if (t + 1 < NK) ldregs((t + 1) * BK);
        mmaStep(t & 1);
        if (t + 1 < NK) dswrite((t + 1) & 1);
        __syncthreads();
    }

    int r0 = (lane >> 4) * 4, cc = lane & 15;
    #pragma unroll
    for (int fm = 0; fm < 2; ++fm) {
        #pragma unroll
        for (int r = 0; r < 4; ++r) {
            int p = m0 + w * 32 + fm * 16 + r0 + r;
            if (p < n) {
                int tok = tok_list ? tok_list[seg + p] : p;
                size_t ob = (size_t)tok * H_DIM + h0 + cc;
                if (w_list) {
                    float wt = w_list[seg + p];
                    #pragma unroll
                    for (int fn = 0; fn < 8; ++fn)
                        atomicAdd(&out[ob + fn * 16], acc[fm][fn][r] * wt);
                } else {
                    #pragma unroll
                    for (int fn = 0; fn < 8; ++fn)
                        out[ob + fn * 16] = acc[fm][fn][r];
                }
            }
        }
    }
}

extern "C" void kernel_launch(void* const* d_in, const int* in_sizes, int n_in,
                              void* d_out, int out_size, void* d_ws, size_t ws_size,
                              hipStream_t stream) {
    const float* x         = (const float*)d_in[0];
    const float* gate_w    = (const float*)d_in[1];
    const float* e_bias    = (const float*)d_in[2];
    const float* gate_proj = (const float*)d_in[3];
    const float* up_proj   = (const float*)d_in[4];
    const float* down_proj = (const float*)d_in[5];
    const float* sgw       = (const float*)d_in[6];
    const float* suw       = (const float*)d_in[7];
    const float* sdw       = (const float*)d_in[8];
    float* out = (float*)d_out;

    char* ws = (char*)d_ws;
    size_t off = 0;
    auto alloc = [&](size_t bytes) -> char* {
        char* p = ws + off;
        off += (bytes + 255) & ~(size_t)255;
        return p;
    };
    float* logits   = (float*)alloc((size_t)T_TOK * 64 * 4);
    int*   topk_idx = (int*)  alloc((size_t)T_TOK * 8 * 4);
    float* topk_w   = (float*)alloc((size_t)T_TOK * 8 * 4);
    int*   counts   = (int*)  alloc(256);   // [64]
    int*   offsets  = (int*)  alloc(512);   // [65]
    int*   fill     = (int*)  alloc(256);   // [64]
    int*   tiles    = (int*)  alloc(MAXT * 4);
    int*   ntiles   = (int*)  alloc(256);
    int*   tok_list = (int*)  alloc((size_t)T_TOK * 8 * 4);
    float* w_list   = (float*)alloc((size_t)T_TOK * 8 * 4);
    u16*   xb       = (u16*)  alloc((size_t)T_TOK * H_DIM * 2);
    u16*   inter    = (u16*)  alloc((size_t)T_TOK * 8 * I_DIM * 2); // reused for shared

    hipMemsetAsync(counts, 0, 1024, stream); // counts + offsets + fill

    k_cvt<<<(T_TOK * H_DIM) / 2048, 256, 0, stream>>>(x, xb);
    k_gate_logits<<<T_TOK / 8, 256, 0, stream>>>(x, gate_w, logits);
    k_topk<<<T_TOK / 256, 256, 0, stream>>>(logits, e_bias, topk_idx, topk_w, counts);
    k_prefix<<<1, 64, 0, stream>>>(counts, offsets, tiles, ntiles);
    k_scatter<<<(T_TOK * 8) / 256, 256, 0, stream>>>(topk_idx, topk_w, offsets, fill, tok_list, w_list);

    // shared experts FIRST: shared k_down does plain stores covering all of out.
    // Grid: x = panel index (padded to multiple of 8 -> fixed XCD per panel),
    //       y = m-tile. All m-tiles of one panel share one XCD's L2 copy of B.
    k_gateup<<<dim3(48, T_TOK / BM), 256, 0, stream>>>(
        xb, sgw, suw, nullptr, nullptr, nullptr, nullptr, inter, SI_DIM);
    k_down<<<dim3(16, T_TOK / BM), 256, 0, stream>>>(
        inter, SI_DIM, sdw, nullptr, nullptr, nullptr, nullptr, nullptr, out);

    // routed experts accumulate on top via atomics; tiles are XCD-grouped.
    k_gateup<<<dim3(MAXT, I_DIM / 64), 256, 0, stream>>>(
        xb, gate_proj, up_proj, offsets, tok_list, tiles, ntiles, inter, I_DIM);
    k_down<<<dim3(MAXT, H_DIM / 128), 256, 0, stream>>>(
        inter, I_DIM, down_proj, offsets, tok_list, tiles, ntiles, w_list, out);
}

// Round 11
// 1300.581 us; speedup vs baseline: 1.2064x; 1.0080x over previous
//
#include <hip/hip_runtime.h>

typedef unsigned short u16;
typedef unsigned int u32;
typedef __attribute__((ext_vector_type(8))) short short8;
typedef __attribute__((ext_vector_type(8))) u16 ushort8;
typedef __attribute__((ext_vector_type(4))) float f32x4;

#define T_TOK 2048
#define H_DIM 2048
#define NEXP 64
#define I_DIM 1408
#define SI_DIM 2816
#define BM 128
#define BK 64
#define MAXT 384

__device__ __forceinline__ u16 f2bf(float f) {
    u32 u = __builtin_bit_cast(u32, f);
    u32 r = u + 0x7FFFu + ((u >> 16) & 1u);
    return (u16)(r >> 16);
}

__device__ __forceinline__ ushort8 cvt8(f32x4 a, f32x4 b) {
    ushort8 o;
    o[0] = f2bf(a[0]); o[1] = f2bf(a[1]); o[2] = f2bf(a[2]); o[3] = f2bf(a[3]);
    o[4] = f2bf(b[0]); o[5] = f2bf(b[1]); o[6] = f2bf(b[2]); o[7] = f2bf(b[3]);
    return o;
}

__device__ __forceinline__ f32x4 mfma16(short8 a, short8 b, f32x4 c) {
    return __builtin_amdgcn_mfma_f32_16x16x32_bf16(a, b, c, 0, 0, 0);
}

// ---------------- x -> bf16 ----------------
__global__ __launch_bounds__(256) void k_cvt(const float* __restrict__ x, u16* __restrict__ xb) {
    int i = (blockIdx.x * 256 + threadIdx.x) * 8;
    f32x4 v0 = *(const f32x4*)(x + i);
    f32x4 v1 = *(const f32x4*)(x + i + 4);
    *(ushort8*)(xb + i) = cvt8(v0, v1);
}

// ---------------- gating logits: f64 accumulation ----------------
__global__ __launch_bounds__(256) void k_gate_logits(const float* __restrict__ x,
        const float* __restrict__ gw, float* __restrict__ logits) {
    __shared__ float xs[8][65];
    __shared__ float wsh[64][65];
    int tid = threadIdx.x;
    int t0 = blockIdx.x * 8;
    double acc0 = 0.0, acc1 = 0.0;
    int e = tid & 63, tg = tid >> 6; // tg in [0,4)
    for (int k0 = 0; k0 < H_DIM; k0 += 64) {
        #pragma unroll
        for (int s = 0; s < 2; ++s) {
            int idx = s * 256 + tid;
            int r = idx >> 6, k = idx & 63;
            xs[r][k] = x[(size_t)(t0 + r) * H_DIM + k0 + k];
        }
        #pragma unroll
        for (int s = 0; s < 16; ++s) {
            int idx = s * 256 + tid;
            int r = idx >> 6, k = idx & 63;
            wsh[r][k] = gw[(size_t)r * H_DIM + k0 + k];
        }
        __syncthreads();
        #pragma unroll 8
        for (int k = 0; k < 64; ++k) {
            double wv = (double)wsh[e][k];
            acc0 += (double)xs[tg][k] * wv;
            acc1 += (double)xs[tg + 4][k] * wv;
        }
        __syncthreads();
    }
    logits[(size_t)(t0 + tg) * NEXP + e] = (float)acc0;
    logits[(size_t)(t0 + tg + 4) * NEXP + e] = (float)acc1;
}

// ---------------- per-token group-restricted top-k ----------------
__global__ __launch_bounds__(256) void k_topk(const float* __restrict__ logits,
        const float* __restrict__ ebias, int* __restrict__ topk_idx,
        float* __restrict__ topk_w, int* __restrict__ counts) {
    __shared__ float bsh[64];
    if (threadIdx.x < 64) bsh[threadIdx.x] = ebias[threadIdx.x];
    __syncthreads();
    int t = blockIdx.x * 256 + threadIdx.x;
    float sc[64];
    #pragma unroll
    for (int e2 = 0; e2 < 64; ++e2) {
        float lg = logits[(size_t)t * 64 + e2];
        sc[e2] = 1.0f / (1.0f + expf(-lg));
    }
    float gsc[8];
    #pragma unroll
    for (int g = 0; g < 8; ++g) {
        float m1 = -1e30f, m2 = -1e30f;
        #pragma unroll
        for (int j = 0; j < 8; ++j) {
            float v = sc[g * 8 + j] + bsh[g * 8 + j];
            if (v > m1) { m2 = m1; m1 = v; }
            else if (v > m2) { m2 = v; }
        }
        gsc[g] = m1 + m2;
    }
    u32 gmask = 0;
    #pragma unroll
    for (int it = 0; it < 4; ++it) {
        float best = -1e30f; int bi = 0;
        #pragma unroll
        for (int g = 0; g < 8; ++g) {
            bool ok = !((gmask >> g) & 1u);
            if (ok && gsc[g] > best) { best = gsc[g]; bi = g; }
        }
        gmask |= 1u << bi;
    }
    unsigned long long avail = 0ull;
    #pragma unroll
    for (int g = 0; g < 8; ++g)
        if ((gmask >> g) & 1u) avail |= (0xFFull << (g * 8));
    float wsum = 0.f;
    int idx[8]; float wv[8];
    #pragma unroll
    for (int it = 0; it < 8; ++it) {
        float best = -1e30f, bw = 0.f; int bi = 0;
        #pragma unroll
        for (int e2 = 0; e2 < 64; ++e2) {
            bool ok = (avail >> e2) & 1ull;
            float v = sc[e2] + bsh[e2];
            if (ok && v > best) { best = v; bi = e2; bw = sc[e2]; }
        }
        avail &= ~(1ull << bi);
        idx[it] = bi; wv[it] = bw; wsum += bw;
    }
    float scale = 2.5f / (wsum + 1e-20f);
    #pragma unroll
    for (int it = 0; it < 8; ++it) {
        topk_idx[t * 8 + it] = idx[it];
        topk_w[t * 8 + it] = wv[it] * scale;
        atomicAdd(&counts[idx[it]], 1);
    }
}

// ---------------- prefix sum + XCD-grouped tile list (BM=128) ----------------
__global__ void k_prefix(const int* __restrict__ counts, int* __restrict__ offsets,
                         int* __restrict__ tiles, int* __restrict__ ntiles) {
    if (threadIdx.x == 0) {
        int run = 0;
        for (int e = 0; e < 64; ++e) { offsets[e] = run; run += counts[e]; }
        offsets[64] = run;
        for (int i = 0; i < MAXT; ++i) tiles[i] = -1;
        int slot[8] = {0, 0, 0, 0, 0, 0, 0, 0};
        int nt = 0;
        for (int e = 0; e < 64; ++e) {
            int xcd = e & 7;
            int c = counts[e];
            for (int m0 = 0; m0 < c; m0 += BM) {
                int pos = xcd + 8 * slot[xcd];
                if (pos < MAXT) { tiles[pos] = (e << 16) | m0; slot[xcd]++; nt++; }
            }
        }
        *ntiles = nt;
    }
}

// ---------------- scatter (t,k) -> per-expert lists ----------------
__global__ __launch_bounds__(256) void k_scatter(const int* __restrict__ topk_idx,
        const float* __restrict__ topk_w, const int* __restrict__ offsets,
        int* __restrict__ fill, int* __restrict__ tok_list, float* __restrict__ w_list) {
    int gid = blockIdx.x * 256 + threadIdx.x;
    int t = gid >> 3;
    int e = topk_idx[gid];
    int pos = offsets[e] + atomicAdd(&fill[e], 1);
    tok_list[pos] = t;
    w_list[pos] = topk_w[gid];
}

// ---------------- fused gate+up+silu*mul grouped GEMM ----------------
// 128m x 64n(gate+up), BK=64, 4 waves. Double-buffered LDS, one barrier/K-step,
// DEPTH-2 register staging: dswrite consumes loads issued one full step earlier.
__global__ __launch_bounds__(256, 2) void k_gateup(
        const u16* __restrict__ xb,
        const float* __restrict__ gate_base, const float* __restrict__ up_base,
        const int* __restrict__ offsets, const int* __restrict__ tok_list,
        const int* __restrict__ tiles, const int* __restrict__ ntiles,
        u16* __restrict__ inter, int Irows) {
    int e, m0, seg, n, i0;
    if (tiles) {
        int tt = tiles[blockIdx.x];
        if (tt < 0) return;
        e = tt >> 16; m0 = tt & 0xFFFF;
        seg = offsets[e]; n = offsets[e + 1] - seg;
        i0 = blockIdx.y * 64;
    } else {
        e = 0; seg = 0; n = T_TOK;
        i0 = blockIdx.x * 64;
        if (i0 >= Irows) return;
        m0 = blockIdx.y * BM;
    }
    if (n <= 0 || m0 >= n) return;

    const float* Bg = gate_base + (size_t)e * Irows * H_DIM;
    const float* Bu = up_base + (size_t)e * Irows * H_DIM;

    __shared__ u16 As[2][BM * BK];    // 2 x 16KB
    __shared__ u16 Bsg[2][64 * BK];   // 2 x 8KB
    __shared__ u16 Bsu[2][64 * BK];   // 2 x 8KB

    int tid = threadIdx.x;
    int w = tid >> 6, lane = tid & 63;

    const u16* asrc[4]; int adst[4];
    #pragma unroll
    for (int s = 0; s < 4; ++s) {
        int slot = s * 256 + tid;
        int r = slot >> 3, cb = slot & 7;
        int p = m0 + r; if (p >= n) p = n - 1;
        int tok = tok_list ? tok_list[seg + p] : p;
        asrc[s] = xb + (size_t)tok * H_DIM + cb * 8;
        adst[s] = r * BK + ((cb ^ (r & 7)) * 8);
    }
    const float* bgsrc[2]; const float* busrc[2]; int bdst[2];
    #pragma unroll
    for (int s = 0; s < 2; ++s) {
        int slot = s * 256 + tid;
        int r = slot >> 3, cb = slot & 7;
        bgsrc[s] = Bg + (size_t)(i0 + r) * H_DIM + cb * 8;
        busrc[s] = Bu + (size_t)(i0 + r) * H_DIM + cb * 8;
        bdst[s] = r * BK + ((cb ^ (r & 7)) * 8);
    }

    f32x4 zero; zero[0] = 0.f; zero[1] = 0.f; zero[2] = 0.f; zero[3] = 0.f;
    f32x4 accg[2][4], accu[2][4];
    #pragma unroll
    for (int a = 0; a < 2; ++a)
        #pragma unroll
        for (int b = 0; b < 4; ++b) { accg[a][b] = zero; accu[a][b] = zero; }

    // two named stage sets (static indexing; rule #20)
    short8 stA0[4], stA1[4];
    f32x4 stG0[2][2], stU0[2][2], stG1[2][2], stU1[2][2];

    auto ldS0 = [&](int t) {
        int k0 = t * BK;
        #pragma unroll
        for (int s = 0; s < 4; ++s) stA0[s] = *(const short8*)(asrc[s] + k0);
        #pragma unroll
        for (int s = 0; s < 2; ++s) {
            stG0[s][0] = *(const f32x4*)(bgsrc[s] + k0);
            stG0[s][1] = *(const f32x4*)(bgsrc[s] + k0 + 4);
            stU0[s][0] = *(const f32x4*)(busrc[s] + k0);
            stU0[s][1] = *(const f32x4*)(busrc[s] + k0 + 4);
        }
    };
    auto ldS1 = [&](int t) {
        int k0 = t * BK;
        #pragma unroll
        for (int s = 0; s < 4; ++s) stA1[s] = *(const short8*)(asrc[s] + k0);
        #pragma unroll
        for (int s = 0; s < 2; ++s) {
            stG1[s][0] = *(const f32x4*)(bgsrc[s] + k0);
            stG1[s][1] = *(const f32x4*)(bgsrc[s] + k0 + 4);
            stU1[s][0] = *(const f32x4*)(busrc[s] + k0);
            stU1[s][1] = *(const f32x4*)(busrc[s] + k0 + 4);
        }
    };
    auto dsw0 = [&]() {   // stage0 -> buf0
        #pragma unroll
        for (int s = 0; s < 4; ++s) *(ushort8*)(&As[0][adst[s]]) = *(const ushort8*)&stA0[s];
        #pragma unroll
        for (int s = 0; s < 2; ++s) {
            *(ushort8*)(&Bsg[0][bdst[s]]) = cvt8(stG0[s][0], stG0[s][1]);
            *(ushort8*)(&Bsu[0][bdst[s]]) = cvt8(stU0[s][0], stU0[s][1]);
        }
    };
    auto dsw1 = [&]() {   // stage1 -> buf1
        #pragma unroll
        for (int s = 0; s < 4; ++s) *(ushort8*)(&As[1][adst[s]]) = *(const ushort8*)&stA1[s];
        #pragma unroll
        for (int s = 0; s < 2; ++s) {
            *(ushort8*)(&Bsg[1][bdst[s]]) = cvt8(stG1[s][0], stG1[s][1]);
            *(ushort8*)(&Bsu[1][bdst[s]]) = cvt8(stU1[s][0], stU1[s][1]);
        }
    };
    auto mmaStep = [&](int buf) {
        #pragma unroll
        for (int ks = 0; ks < 2; ++ks) {
            short8 a[2];
            #pragma unroll
            for (int fm = 0; fm < 2; ++fm) {
                int row = w * 32 + fm * 16 + (lane & 15);
                int cb = ks * 4 + (lane >> 4);
                a[fm] = *(const short8*)(&As[buf][row * BK + ((cb ^ (row & 7)) * 8)]);
            }
            #pragma unroll
            for (int fn = 0; fn < 4; ++fn) {
                int brow = fn * 16 + (lane & 15);
                int cb = ks * 4 + (lane >> 4);
                int boff = brow * BK + ((cb ^ (brow & 7)) * 8);
                short8 bg = *(const short8*)(&Bsg[buf][boff]);
                short8 bu = *(const short8*)(&Bsu[buf][boff]);
                accg[0][fn] = mfma16(a[0], bg, accg[0][fn]);
                accg[1][fn] = mfma16(a[1], bg, accg[1][fn]);
                accu[0][fn] = mfma16(a[0], bu, accu[0][fn]);
                accu[1][fn] = mfma16(a[1], bu, accu[1][fn]);
            }
        }
    };

    const int NK = H_DIM / BK; // 32, even
    ldS0(0); dsw0();
    ldS1(1);                       // in flight across the first barrier
    __syncthreads();
    for (int t = 0; t < NK; t += 2) {
        // even: consume buf0 (tile t); stage1 holds tile t+1 (issued >=1 step ago)
        if (t + 2 < NK) ldS0(t + 2);
        mmaStep(0);
        if (t + 1 < NK) dsw1();
        __syncthreads();
        if (t + 1 < NK) {
            // odd: consume buf1 (tile t+1); stage0 holds tile t+2 (1 step old)
            if (t + 3 < NK) ldS1(t + 3);
            mmaStep(1);
            if (t + 2 < NK) dsw0();
            __syncthreads();
        }
    }

    int r0 = (lane >> 4) * 4, cc = lane & 15;
    #pragma unroll
    for (int fm = 0; fm < 2; ++fm) {
        #pragma unroll
        for (int r = 0; r < 4; ++r) {
            int p = m0 + w * 32 + fm * 16 + r0 + r;
            if (p < n) {
                size_t rowb = (size_t)(seg + p) * Irows + i0;
                #pragma unroll
                for (int fn = 0; fn < 4; ++fn) {
                    float g = accg[fm][fn][r], u = accu[fm][fn][r];
                    float val = g / (1.0f + expf(-g)) * u;
                    inter[rowb + fn * 16 + cc] = f2bf(val);
                }
            }
        }
    }
}

// ---------------- down-proj grouped GEMM ----------------
// 128m x 128n, BK=64, 4 waves. Same dbuf + depth-2 register staging.
// w_list==nullptr => plain store (shared experts, run FIRST); else atomicAdd*wt.
__global__ __launch_bounds__(256, 2) void k_down(
        const u16* __restrict__ inter, int Kdim,
        const float* __restrict__ down_base,
        const int* __restrict__ offsets, const int* __restrict__ tok_list,
        const int* __restrict__ tiles, const int* __restrict__ ntiles,
        const float* __restrict__ w_list,
        float* __restrict__ out) {
    int e, m0, seg, n, h0;
    if (tiles) {
        int tt = tiles[blockIdx.x];
        if (tt < 0) return;
        e = tt >> 16; m0 = tt & 0xFFFF;
        seg = offsets[e]; n = offsets[e + 1] - seg;
        h0 = blockIdx.y * 128;
    } else {
        e = 0; seg = 0; n = T_TOK;
        h0 = blockIdx.x * 128;
        m0 = blockIdx.y * BM;
    }
    if (n <= 0 || m0 >= n) return;

    const float* Bd = down_base + (size_t)e * H_DIM * Kdim;

    __shared__ u16 As[2][BM * BK];    // 2 x 16KB
    __shared__ u16 Bs[2][128 * BK];   // 2 x 16KB

    int tid = threadIdx.x;
    int w = tid >> 6, lane = tid & 63;

    const u16* asrc[4]; int adst[4];
    #pragma unroll
    for (int s = 0; s < 4; ++s) {
        int slot = s * 256 + tid;
        int r = slot >> 3, cb = slot & 7;
        int p = m0 + r; if (p >= n) p = n - 1;
        asrc[s] = inter + (size_t)(seg + p) * Kdim + cb * 8;
        adst[s] = r * BK + ((cb ^ (r & 7)) * 8);
    }
    const float* bsrc[4]; int bdst[4];
    #pragma unroll
    for (int s = 0; s < 4; ++s) {
        int slot = s * 256 + tid;
        int r = slot >> 3, cb = slot & 7;
        bsrc[s] = Bd + (size_t)(h0 + r) * Kdim + cb * 8;
        bdst[s] = r * BK + ((cb ^ (r & 7)) * 8);
    }

    f32x4 zero; zero[0] = 0.f; zero[1] = 0.f; zero[2] = 0.f; zero[3] = 0.f;
    f32x4 acc[2][8];
    #pragma unroll
    for (int a = 0; a < 2; ++a)
        #pragma unroll
        for (int b = 0; b < 8; ++b) acc[a][b] = zero;

    short8 stA0[4], stA1[4];
    f32x4 stB0[4][2], stB1[4][2];

    auto ldS0 = [&](int t) {
        int k0 = t * BK;
        #pragma unroll
        for (int s = 0; s < 4; ++s) stA0[s] = *(const short8*)(asrc[s] + k0);
        #pragma unroll
        for (int s = 0; s < 4; ++s) {
            stB0[s][0] = *(const f32x4*)(bsrc[s] + k0);
            stB0[s][1] = *(const f32x4*)(bsrc[s] + k0 + 4);
        }
    };
    auto ldS1 = [&](int t) {
        int k0 = t * BK;
        #pragma unroll
        for (int s = 0; s < 4; ++s) stA1[s] = *(const short8*)(asrc[s] + k0);
        #pragma unroll
        for (int s = 0; s < 4; ++s) {
            stB1[s][0] = *(const f32x4*)(bsrc[s] + k0);
            stB1[s][1] = *(const f32x4*)(bsrc[s] + k0 + 4);
        }
    };
    auto dsw0 = [&]() {
        #pragma unroll
        for (int s = 0; s < 4; ++s) *(ushort8*)(&As[0][adst[s]]) = *(const ushort8*)&stA0[s];
        #pragma unroll
        for (int s = 0; s < 4; ++s)
            *(ushort8*)(&Bs[0][bdst[s]]) = cvt8(stB0[s][0], stB0[s][1]);
    };
    auto dsw1 = [&]() {
        #pragma unroll
        for (int s = 0; s < 4; ++s) *(ushort8*)(&As[1][adst[s]]) = *(const ushort8*)&stA1[s];
        #pragma unroll
        for (int s = 0; s < 4; ++s)
            *(ushort8*)(&Bs[1][bdst[s]]) = cvt8(stB1[s][0], stB1[s][1]);
    };
    auto mmaStep = [&](int buf) {
        #pragma unroll
        for (int ks = 0; ks < 2; ++ks) {
            short8 a[2];
            #pragma unroll
            for (int fm = 0; fm < 2; ++fm) {
                int row = w * 32 + fm * 16 + (lane & 15);
                int cb = ks * 4 + (lane >> 4);
                a[fm] = *(const short8*)(&As[buf][row * BK + ((cb ^ (row & 7)) * 8)]);
            }
            #pragma unroll
            for (int fn = 0; fn < 8; ++fn) {
                int brow = fn * 16 + (lane & 15);
                int cb = ks * 4 + (lane >> 4);
                short8 b = *(const short8*)(&Bs[buf][brow * BK + ((cb ^ (brow & 7)) * 8)]);
                acc[0][fn] = mfma16(a[0], b, acc[0][fn]);
                acc[1][fn] = mfma16(a[1], b, acc[1][fn]);
            }
        }
    };

    const int NK = Kdim / BK; // 22 or 44, even
    ldS0(0); dsw0();
    ldS1(1);
    __syncthreads();
    for (int t = 0; t < NK; t += 2) {
        if (t + 2 < NK) ldS0(t + 2);
        mmaStep(0);
        if (t + 1 < NK) dsw1();
        __syncthreads();
        if (t + 1 < NK) {
            if (t + 3 < NK) ldS1(t + 3);
            mmaStep(1);
            if (t + 2 < NK) dsw0();
            __syncthreads();
        }
    }

    int r0 = (lane >> 4) * 4, cc = lane & 15;
    #pragma unroll
    for (int fm = 0; fm < 2; ++fm) {
        #pragma unroll
        for (int r = 0; r < 4; ++r) {
            int p = m0 + w * 32 + fm * 16 + r0 + r;
            if (p < n) {
                int tok = tok_list ? tok_list[seg + p] : p;
                size_t ob = (size_t)tok * H_DIM + h0 + cc;
                if (w_list) {
                    float wt = w_list[seg + p];
                    #pragma unroll
                    for (int fn = 0; fn < 8; ++fn)
                        atomicAdd(&out[ob + fn * 16], acc[fm][fn][r] * wt);
                } else {
                    #pragma unroll
                    for (int fn = 0; fn < 8; ++fn)
                        out[ob + fn * 16] = acc[fm][fn][r];
                }
            }
        }
    }
}

extern "C" void kernel_launch(void* const* d_in, const int* in_sizes, int n_in,
                              void* d_out, int out_size, void* d_ws, size_t ws_size,
                              hipStream_t stream) {
    const float* x         = (const float*)d_in[0];
    const float* gate_w    = (const float*)d_in[1];
    const float* e_bias    = (const float*)d_in[2];
    const float* gate_proj = (const float*)d_in[3];
    const float* up_proj   = (const float*)d_in[4];
    const float* down_proj = (const float*)d_in[5];
    const float* sgw       = (const float*)d_in[6];
    const float* suw       = (const float*)d_in[7];
    const float* sdw       = (const float*)d_in[8];
    float* out = (float*)d_out;

    char* ws = (char*)d_ws;
    size_t off = 0;
    auto alloc = [&](size_t bytes) -> char* {
        char* p = ws + off;
        off += (bytes + 255) & ~(size_t)255;
        return p;
    };
    float* logits   = (float*)alloc((size_t)T_TOK * 64 * 4);
    int*   topk_idx = (int*)  alloc((size_t)T_TOK * 8 * 4);
    float* topk_w   = (float*)alloc((size_t)T_TOK * 8 * 4);
    int*   counts   = (int*)  alloc(256);   // [64]
    int*   offsets  = (int*)  alloc(512);   // [65]
    int*   fill     = (int*)  alloc(256);   // [64]
    int*   tiles    = (int*)  alloc(MAXT * 4);
    int*   ntiles   = (int*)  alloc(256);
    int*   tok_list = (int*)  alloc((size_t)T_TOK * 8 * 4);
    float* w_list   = (float*)alloc((size_t)T_TOK * 8 * 4);
    u16*   xb       = (u16*)  alloc((size_t)T_TOK * H_DIM * 2);
    u16*   inter    = (u16*)  alloc((size_t)T_TOK * 8 * I_DIM * 2); // reused for shared

    hipMemsetAsync(counts, 0, 1024, stream); // counts + offsets + fill

    k_cvt<<<(T_TOK * H_DIM) / 2048, 256, 0, stream>>>(x, xb);
    k_gate_logits<<<T_TOK / 8, 256, 0, stream>>>(x, gate_w, logits);
    k_topk<<<T_TOK / 256, 256, 0, stream>>>(logits, e_bias, topk_idx, topk_w, counts);
    k_prefix<<<1, 64, 0, stream>>>(counts, offsets, tiles, ntiles);
    k_scatter<<<(T_TOK * 8) / 256, 256, 0, stream>>>(topk_idx, topk_w, offsets, fill, tok_list, w_list);

    // shared experts FIRST: shared k_down does plain stores covering all of out.
    k_gateup<<<dim3(48, T_TOK / BM), 256, 0, stream>>>(
        xb, sgw, suw, nullptr, nullptr, nullptr, nullptr, inter, SI_DIM);
    k_down<<<dim3(16, T_TOK / BM), 256, 0, stream>>>(
        inter, SI_DIM, sdw, nullptr, nullptr, nullptr, nullptr, nullptr, out);

    // routed experts accumulate on top via atomics; tiles are XCD-grouped.
    k_gateup<<<dim3(MAXT, I_DIM / 64), 256, 0, stream>>>(
        xb, gate_proj, up_proj, offsets, tok_list, tiles, ntiles, inter, I_DIM);
    k_down<<<dim3(MAXT, H_DIM / 128), 256, 0, stream>>>(
        inter, I_DIM, down_proj, offsets, tok_list, tiles, ntiles, w_list, out);
}